// Round 1
// baseline (220.693 us; speedup 1.0000x reference)
//
#include <hip/hip_runtime.h>

#define NPTS 100000
#define P 64
#define C 128

typedef __bf16 bf16_t;
typedef __bf16 bf16x8 __attribute__((ext_vector_type(8)));
typedef float floatx4 __attribute__((ext_vector_type(4)));

// Workspace layout (bytes):
//   [0,      65536)    W1t bf16 [256][128]   (s1 folded, transposed: [n][k])
//   [65536, 131072)    W2t bf16 [128][256]   (s2 folded, transposed)
//   [131072,163840)    Wat bf16 [128][128]   (transposed)
//   [163840,294912)    acc f32  [64][2][256] (per plane: sel{on,off} x {num[128],den[128]})

__global__ __launch_bounds__(256) void prep_kernel(
    const float* __restrict__ W1, const float* __restrict__ s1,
    const float* __restrict__ W2, const float* __restrict__ s2,
    const float* __restrict__ Wa,
    bf16_t* __restrict__ W1t, bf16_t* __restrict__ W2t, bf16_t* __restrict__ Wat,
    float* __restrict__ acc)
{
  int i0 = blockIdx.x * blockDim.x + threadIdx.x;
  int stride = gridDim.x * blockDim.x;
  for (int i = i0; i < 256 * 128; i += stride) {          // W1t[n][k] = W1[k][n]*s1[n]
    int n = i >> 7, k = i & 127;
    W1t[i] = (bf16_t)(W1[k * 256 + n] * s1[n]);
  }
  for (int i = i0; i < 128 * 256; i += stride) {          // W2t[n][k] = W2[k][n]*s2[n]
    int n = i >> 8, k = i & 255;
    W2t[i] = (bf16_t)(W2[k * 128 + n] * s2[n]);
  }
  for (int i = i0; i < 128 * 128; i += stride) {          // Wat[n][k] = Wa[k][n]
    int n = i >> 7, k = i & 127;
    Wat[i] = (bf16_t)(Wa[k * 128 + n]);
  }
  for (int i = i0; i < P * 512; i += stride) acc[i] = 0.f; // zero accumulator each launch
}

// Fused: feature -> h -> h2 -> (logit, a=h2@Wa) -> per-plane masked-softmax
// accumulation via global f32 atomics. No rec array, no pool kernel.
__global__ __launch_bounds__(256) void main_kernel(
    const float* __restrict__ feature, const float* __restrict__ xyz,
    const float* __restrict__ b1, const float* __restrict__ b2,
    const float* __restrict__ W3, const float* __restrict__ b3,
    const float* __restrict__ ctr, const float* __restrict__ nrm,
    const float* __restrict__ pmn, const float* __restrict__ pmx,
    const bf16_t* __restrict__ W1t, const bf16_t* __restrict__ W2t,
    const bf16_t* __restrict__ Wat,
    float* __restrict__ acc, float* __restrict__ out_logit)
{
  // LDS: A1 bf16[64][136] (feature tile; later h2)
  //      Hs bf16[64][264] (h; later overlaid by aB bf16[64][136])
  //      w3S f32[128] | xyzS f32[64][3] | lgS f32[64]
  __shared__ __align__(16) char smem[52736];
  bf16_t* A1   = (bf16_t*)smem;
  bf16_t* Hs   = (bf16_t*)(smem + 17408);
  bf16_t* aB   = (bf16_t*)(smem + 17408);          // overlays Hs after GEMM2
  float*  w3S  = (float*)(smem + 51200);
  float*  xyzS = (float*)(smem + 51712);
  float*  lgS  = (float*)(smem + 52480);

  const int tid  = threadIdx.x;
  const int wave = tid >> 6, lane = tid & 63;
  const int quad = lane >> 4, l16 = lane & 15;
  const int m0 = blockIdx.x * 64;

  if (tid < 128) w3S[tid] = W3[tid];
  if (tid < 192) {                                  // stage xyz tile (64 pts x 3)
    int gi = m0 * 3 + tid;
    xyzS[tid] = (gi < NPTS * 3) ? xyz[gi] : 0.f;
  }

  // ---- stage feature tile (fp32 -> bf16) ----
  for (int i = tid; i < 64 * 32; i += 256) {   // 32 float4 per row
    int r = i >> 5, c4 = i & 31;
    float4 v = make_float4(0.f, 0.f, 0.f, 0.f);
    if (m0 + r < NPTS) v = *(const float4*)(feature + (size_t)(m0 + r) * C + c4 * 4);
    bf16_t* dst = A1 + r * 136 + c4 * 4;
    dst[0] = (bf16_t)v.x; dst[1] = (bf16_t)v.y; dst[2] = (bf16_t)v.z; dst[3] = (bf16_t)v.w;
  }
  __syncthreads();

  const floatx4 zero4 = {0.f, 0.f, 0.f, 0.f};

  // ---- GEMM1: h[64][256] = relu(A1 @ W1' + b1). Wave owns n-cols [wave*64,+64) ----
  {
    floatx4 acc1[4][4];
#pragma unroll
    for (int mt = 0; mt < 4; ++mt)
#pragma unroll
      for (int nt = 0; nt < 4; ++nt) acc1[mt][nt] = zero4;
#pragma unroll
    for (int kt = 0; kt < 4; ++kt) {
      bf16x8 af[4], bfr[4];
#pragma unroll
      for (int mt = 0; mt < 4; ++mt)
        af[mt] = *(const bf16x8*)(A1 + (mt * 16 + l16) * 136 + kt * 32 + quad * 8);
#pragma unroll
      for (int nt = 0; nt < 4; ++nt)
        bfr[nt] = *(const bf16x8*)(W1t + (wave * 64 + nt * 16 + l16) * 128 + kt * 32 + quad * 8);
#pragma unroll
      for (int mt = 0; mt < 4; ++mt)
#pragma unroll
        for (int nt = 0; nt < 4; ++nt)
          acc1[mt][nt] = __builtin_amdgcn_mfma_f32_16x16x32_bf16(af[mt], bfr[nt], acc1[mt][nt], 0, 0, 0);
    }
#pragma unroll
    for (int nt = 0; nt < 4; ++nt) {
      int col = wave * 64 + nt * 16 + l16;
      float bias = b1[col];
#pragma unroll
      for (int mt = 0; mt < 4; ++mt)
#pragma unroll
        for (int r = 0; r < 4; ++r) {
          float hv = fmaxf(acc1[mt][nt][r] + bias, 0.f);
          Hs[(mt * 16 + quad * 4 + r) * 264 + col] = (bf16_t)hv;
        }
    }
  }
  __syncthreads();

  // ---- GEMM2: h2[64][128] = relu(h @ W2' + b2) -> bf16 into A1 region ----
  {
    floatx4 acc2[4][2];
#pragma unroll
    for (int mt = 0; mt < 4; ++mt) { acc2[mt][0] = zero4; acc2[mt][1] = zero4; }
#pragma unroll
    for (int kt = 0; kt < 8; ++kt) {
      bf16x8 af[4], bfr[2];
#pragma unroll
      for (int mt = 0; mt < 4; ++mt)
        af[mt] = *(const bf16x8*)(Hs + (mt * 16 + l16) * 264 + kt * 32 + quad * 8);
#pragma unroll
      for (int nt = 0; nt < 2; ++nt)
        bfr[nt] = *(const bf16x8*)(W2t + (wave * 32 + nt * 16 + l16) * 256 + kt * 32 + quad * 8);
#pragma unroll
      for (int mt = 0; mt < 4; ++mt)
#pragma unroll
        for (int nt = 0; nt < 2; ++nt)
          acc2[mt][nt] = __builtin_amdgcn_mfma_f32_16x16x32_bf16(af[mt], bfr[nt], acc2[mt][nt], 0, 0, 0);
    }
#pragma unroll
    for (int nt = 0; nt < 2; ++nt) {
      int col = wave * 32 + nt * 16 + l16;
      float bias = b2[col];
#pragma unroll
      for (int mt = 0; mt < 4; ++mt)
#pragma unroll
        for (int r = 0; r < 4; ++r) {
          float hv = fmaxf(acc2[mt][nt][r] + bias, 0.f);
          A1[(mt * 16 + quad * 4 + r) * 136 + col] = (bf16_t)hv;
        }
    }
  }
  __syncthreads();   // all GEMM2 Hs-reads done; A1 now h2

  // ---- GEMMa: a[64][128] = h2 @ Wa -> bf16 into aB (overlays Hs) ----
  {
    floatx4 acca[4][2];
#pragma unroll
    for (int mt = 0; mt < 4; ++mt) { acca[mt][0] = zero4; acca[mt][1] = zero4; }
#pragma unroll
    for (int kt = 0; kt < 4; ++kt) {
      bf16x8 af[4], bfr[2];
#pragma unroll
      for (int mt = 0; mt < 4; ++mt)
        af[mt] = *(const bf16x8*)(A1 + (mt * 16 + l16) * 136 + kt * 32 + quad * 8);
#pragma unroll
      for (int nt = 0; nt < 2; ++nt)
        bfr[nt] = *(const bf16x8*)(Wat + (wave * 32 + nt * 16 + l16) * 128 + kt * 32 + quad * 8);
#pragma unroll
      for (int mt = 0; mt < 4; ++mt)
#pragma unroll
        for (int nt = 0; nt < 2; ++nt)
          acca[mt][nt] = __builtin_amdgcn_mfma_f32_16x16x32_bf16(af[mt], bfr[nt], acca[mt][nt], 0, 0, 0);
    }
#pragma unroll
    for (int nt = 0; nt < 2; ++nt) {
      int col = wave * 32 + nt * 16 + l16;
#pragma unroll
      for (int mt = 0; mt < 4; ++mt)
#pragma unroll
        for (int r = 0; r < 4; ++r)
          aB[(mt * 16 + quad * 4 + r) * 136 + col] = (bf16_t)acca[mt][nt][r];
    }
  }
  __syncthreads();

  // ---- logit: 4 threads/point, 32 channels each; also stash logit in LDS ----
  {
    const int m = tid >> 2, g = tid & 3, c0g = g * 32;
    const int mg = m0 + m;
    float lsum = 0.f;
#pragma unroll 8
    for (int c = 0; c < 32; ++c)
      lsum += (float)A1[m * 136 + c0g + c] * w3S[c0g + c];
    lsum += __shfl_xor(lsum, 1);
    lsum += __shfl_xor(lsum, 2);
    if (g == 0) {
      float lg = lsum + b3[0];
      lgS[m] = lg;
      if (mg < NPTS) out_logit[mg] = lg;
    }
  }
  __syncthreads();   // lgS visible to all; A1 (h2) and aB (a) still live

  // ---- fused attention pooling: lane = plane (P==64==wave width) ----
  {
    // per-lane plane params
    const float nx = nrm[lane * 3], ny = nrm[lane * 3 + 1], nz = nrm[lane * 3 + 2];
    const float offsP = ctr[lane * 3] * nx + ctr[lane * 3 + 1] * ny + ctr[lane * 3 + 2] * nz;
    const float mnx = pmn[lane * 3], mny = pmn[lane * 3 + 1];
    const float mxx = pmx[lane * 3], mxy = pmx[lane * 3 + 1];

    // wave w owns points [w*16, w*16+16)
    for (int s = 0; s < 16; ++s) {
      const int pt = wave * 16 + s;
      const bool valid = (m0 + pt) < NPTS;
      const float x = xyzS[pt * 3], y = xyzS[pt * 3 + 1], z = xyzS[pt * 3 + 2];
      const float proj = x * nx + y * ny + z * nz;
      const bool hit = valid && (fabsf(proj - offsP) < 0.1f) &&
                       (x >= mnx) && (x < mxx) && (y >= mny) && (y < mxy);
      unsigned long long mball = __ballot(hit);
      if (!mball) continue;                         // wave-uniform

      const int sel = (lgS[pt] > 0.f) ? 0 : 1;      // on=0, off=1
      // lane owns channels 2*lane, 2*lane+1 of this point's a/h2 rows
      const unsigned ap = ((const unsigned*)(aB + pt * 136))[lane];
      const unsigned hp = ((const unsigned*)(A1 + pt * 136))[lane];
      const float a0 = __uint_as_float(ap << 16);
      const float a1 = __uint_as_float(ap & 0xffff0000u);
      const float h0 = __uint_as_float(hp << 16);
      const float h1 = __uint_as_float(hp & 0xffff0000u);
      const float e0 = __expf(a0), e1 = __expf(a1);
      const float eh0 = e0 * h0, eh1 = e1 * h1;

      while (mball) {                               // one iteration per hit plane
        const int pl = __builtin_ctzll(mball);
        mball &= mball - 1;
        float* ab = acc + (size_t)pl * 512 + sel * 256;   // num[128] | den[128]
        atomicAdd(ab + 2 * lane,           eh0);
        atomicAdd(ab + 2 * lane + 1,       eh1);
        atomicAdd(ab + 128 + 2 * lane,     e0);
        atomicAdd(ab + 128 + 2 * lane + 1, e1);
      }
    }
  }
}

// Finalize: agg = num/(den+1e-9), relu(agg@Wm+bm), append ori.
__global__ __launch_bounds__(128) void finalize_kernel(
    const float* __restrict__ acc,
    const float* __restrict__ Wm, const float* __restrict__ bm,
    const float* __restrict__ ctr, const float* __restrict__ nrm,
    const float* __restrict__ pmn, const float* __restrict__ pmx,
    float* __restrict__ out)
{
  int sel = blockIdx.x >> 6, p = blockIdx.x & 63;
  int j = threadIdx.x;
  const float* ab = acc + (size_t)p * 512 + sel * 256;
  float num = ab[j], den = ab[128 + j];
  __shared__ float aggS[128];
  aggS[j] = num / (den + 1e-9f);
  __syncthreads();
  float s = bm[j];
#pragma unroll 4
  for (int c = 0; c < C; ++c) s += aggS[c] * Wm[c * C + j];
  s = fmaxf(s, 0.f);
  float* dst = out + NPTS + sel * (P * 140) + p * 140;
  dst[j] = s;
  if (j < 12) {
    float v;
    if (j < 3)      v = ctr[p * 3 + j];
    else if (j < 6) v = nrm[p * 3 + j - 3];
    else if (j < 9) v = pmn[p * 3 + j - 6];
    else            v = pmx[p * 3 + j - 9];
    dst[C + j] = v;
  }
}

extern "C" void kernel_launch(void* const* d_in, const int* in_sizes, int n_in,
                              void* d_out, int out_size, void* d_ws, size_t ws_size,
                              hipStream_t stream)
{
  const float* feature = (const float*)d_in[0];
  const float* xyz     = (const float*)d_in[1];
  const float* ctr     = (const float*)d_in[2];
  const float* nrm     = (const float*)d_in[3];
  const float* pmn     = (const float*)d_in[4];
  const float* pmx     = (const float*)d_in[5];
  const float* W1      = (const float*)d_in[6];
  const float* s1      = (const float*)d_in[7];
  const float* b1      = (const float*)d_in[8];
  const float* W2      = (const float*)d_in[9];
  const float* s2      = (const float*)d_in[10];
  const float* b2      = (const float*)d_in[11];
  const float* W3      = (const float*)d_in[12];
  const float* b3      = (const float*)d_in[13];
  const float* Wa      = (const float*)d_in[14];
  const float* Wm      = (const float*)d_in[15];
  const float* bm      = (const float*)d_in[16];
  float* out = (float*)d_out;

  char* ws = (char*)d_ws;
  bf16_t* W1t = (bf16_t*)(ws);
  bf16_t* W2t = (bf16_t*)(ws + 65536);
  bf16_t* Wat = (bf16_t*)(ws + 131072);
  float*  acc = (float*)(ws + 163840);                       // 64*512 f32 = 128KB

  prep_kernel<<<64, 256, 0, stream>>>(W1, s1, W2, s2, Wa, W1t, W2t, Wat, acc);
  main_kernel<<<(NPTS + 63) / 64, 256, 0, stream>>>(
      feature, xyz, b1, b2, W3, b3, ctr, nrm, pmn, pmx, W1t, W2t, Wat, acc, out);
  finalize_kernel<<<128, 128, 0, stream>>>(acc, Wm, bm, ctr, nrm, pmn, pmx, out);
}